// Round 7
// baseline (279.359 us; speedup 1.0000x reference)
//
#include <hip/hip_runtime.h>
#include <math.h>

#define EPS  1e-5f
#define EPS2 1e-10f
#define MAXN (1.0f - EPS)

using short8  = __attribute__((ext_vector_type(8))) short;
using floatx4 = __attribute__((ext_vector_type(4))) float;

// DPP cross-lane: pure VALU, never touches the LDS pipe
template <int CTRL>
static __device__ __forceinline__ float qperm(float x) {
  return __int_as_float(__builtin_amdgcn_update_dpp(
      __float_as_int(x), __float_as_int(x), CTRL, 0xF, 0xF, false));
}
#define QP_XOR1    0xB1   // quad_perm [1,0,3,2]
#define QP_XOR2    0x4E   // quad_perm [2,3,0,1]
#define QP_HALFMIR 0x141  // row_half_mirror: lane -> lane^7 within 8

// RNE fp32 -> bf16 split helpers
static __device__ __forceinline__ short bf16_rne(float x) {
  unsigned u = __float_as_uint(x);
  unsigned r = u + 0x7FFFu + ((u >> 16) & 1u);
  return (short)(r >> 16);
}
static __device__ __forceinline__ float bf16_tof(short h) {
  return __uint_as_float(((unsigned)(unsigned short)h) << 16);
}

// logmap scale factor from row sumsq
static __device__ __forceinline__ float logmap_f(float ss) {
  const float r = sqrtf(fmaxf(ss, EPS2));
  float at;
  if (r >= MAXN) {
    at = 0.5f * logf((r * (2.0f - EPS) + EPS) / (EPS * (1.0f + r)));
  } else {
    at = 0.5f * logf((1.0f + r) / (1.0f - r));
  }
  return (1.0f + EPS) * at / r;
}

// ---------- K2: C = f[row]*(A @ W^T) via 3-term bf16-split MFMA ----------
// Row-norm fused: each block reads its 64 A-rows fully across the K loop, so
// the logmap scale f is computed in-block (DPP quad reduce) -- no k_rownorm.
__global__ __launch_bounds__(256) void k_gemm_mfma(
    const float* __restrict__ A0, const float* __restrict__ A1, const float* __restrict__ A2,
    const float* __restrict__ W0, const float* __restrict__ W1, const float* __restrict__ W2,
    float* __restrict__ Cbase) {
  const int z = blockIdx.z;
  const float* A = (z == 0) ? A0 : ((z == 1) ? A1 : A2);
  const float* W = (z == 0) ? W0 : ((z == 1) ? W1 : W2);
  float* C = Cbase + (size_t)z * (2048 * 512);
  __shared__ short Ahi[64][72], Alo[64][72], Whi[64][72], Wlo[64][72];
  __shared__ float f_lds[64];
  const int t = threadIdx.x;
  const int n0 = blockIdx.x * 64;   // M offset (rows, 2048)
  const int m0 = blockIdx.y * 64;   // N offset (cols, 512)
  const int row = t >> 2, c0 = (t & 3) * 16;
  const int w = t >> 6, lane = t & 63;
  const int quad = lane >> 4, l16 = lane & 15;
  const int mw = (w & 1) * 32, nw = (w >> 1) * 32;
  floatx4 acc[2][2];
#pragma unroll
  for (int i = 0; i < 2; ++i)
#pragma unroll
    for (int j = 0; j < 2; ++j) acc[i][j] = (floatx4){0.f, 0.f, 0.f, 0.f};
  float ssq = 0.0f;

  for (int k0 = 0; k0 < 512; k0 += 64) {
    float4 av[4], wv[4];
#pragma unroll
    for (int i = 0; i < 4; ++i) {
      av[i] = *(const float4*)&A[(size_t)(n0 + row) * 512 + k0 + c0 + 4 * i];
      wv[i] = *(const float4*)&W[(size_t)(m0 + row) * 512 + k0 + c0 + 4 * i];
    }
    __syncthreads();
#pragma unroll
    for (int i = 0; i < 4; ++i) {
      const float a4[4] = {av[i].x, av[i].y, av[i].z, av[i].w};
      const float w4[4] = {wv[i].x, wv[i].y, wv[i].z, wv[i].w};
#pragma unroll
      for (int e = 0; e < 4; ++e) {
        ssq = fmaf(a4[e], a4[e], ssq);
        const short ah = bf16_rne(a4[e]);
        const short wh = bf16_rne(w4[e]);
        Ahi[row][c0 + 4 * i + e] = ah;
        Alo[row][c0 + 4 * i + e] = bf16_rne(a4[e] - bf16_tof(ah));
        Whi[row][c0 + 4 * i + e] = wh;
        Wlo[row][c0 + 4 * i + e] = bf16_rne(w4[e] - bf16_tof(wh));
      }
    }
    __syncthreads();
#pragma unroll
    for (int kk = 0; kk < 64; kk += 32) {
      short8 ah[2], al[2], bh[2], bl[2];
#pragma unroll
      for (int i = 0; i < 2; ++i) {
        ah[i] = *(const short8*)&Ahi[mw + i * 16 + l16][kk + quad * 8];
        al[i] = *(const short8*)&Alo[mw + i * 16 + l16][kk + quad * 8];
        bh[i] = *(const short8*)&Whi[nw + i * 16 + l16][kk + quad * 8];
        bl[i] = *(const short8*)&Wlo[nw + i * 16 + l16][kk + quad * 8];
      }
#pragma unroll
      for (int i = 0; i < 2; ++i)
#pragma unroll
        for (int j = 0; j < 2; ++j) {
          acc[i][j] = __builtin_amdgcn_mfma_f32_16x16x32_bf16(ah[i], bh[j], acc[i][j], 0, 0, 0);
          acc[i][j] = __builtin_amdgcn_mfma_f32_16x16x32_bf16(ah[i], bl[j], acc[i][j], 0, 0, 0);
          acc[i][j] = __builtin_amdgcn_mfma_f32_16x16x32_bf16(al[i], bh[j], acc[i][j], 0, 0, 0);
        }
    }
  }
  // fused rownorm: threads 4r..4r+3 form a quad for row r
  ssq += qperm<QP_XOR1>(ssq);
  ssq += qperm<QP_XOR2>(ssq);
  if ((t & 3) == 0) f_lds[row] = logmap_f(ssq);
  __syncthreads();
#pragma unroll
  for (int i = 0; i < 2; ++i) {
    const int lrow_base = mw + i * 16 + quad * 4;
#pragma unroll
    for (int r = 0; r < 4; ++r) {
      const float fv = f_lds[lrow_base + r];
#pragma unroll
      for (int j = 0; j < 2; ++j)
        C[(size_t)(n0 + lrow_base + r) * 512 + m0 + nw + j * 16 + l16] = fv * acc[i][j][r];
    }
  }
}

// ---------- K3: expmap0 + mobius-add bias; per-head project + norms ----------
__global__ __launch_bounds__(256) void k_post(const float* __restrict__ tin,
                                              const float* __restrict__ b0,
                                              const float* __restrict__ b1,
                                              const float* __restrict__ b2,
                                              float* __restrict__ o0, float* __restrict__ o1,
                                              float* __restrict__ o2,
                                              float* __restrict__ nrm0, float* __restrict__ nrm1,
                                              float* __restrict__ nrm2,
                                              float* __restrict__ rowsum_init, int final_mode) {
  const int nrow = blockIdx.x, z = blockIdx.y, t = threadIdx.x;
  const float* tv = tin + ((size_t)z * 2048 + nrow) * 512;
  const float* bias = (z == 0) ? b0 : ((z == 1) ? b1 : b2);
  const int e0 = 2 * t;
  const float2 tp = *(const float2*)&tv[e0];
  const float2 bp = *(const float2*)&bias[e0];
  float p_tt = tp.x * tp.x + tp.y * tp.y;
  float p_tb = tp.x * bp.x + tp.y * bp.y;
  float p_bb = bp.x * bp.x + bp.y * bp.y;
#pragma unroll
  for (int m = 32; m; m >>= 1) {
    p_tt += __shfl_xor(p_tt, m, 64);
    p_tb += __shfl_xor(p_tb, m, 64);
    p_bb += __shfl_xor(p_bb, m, 64);
  }
  __shared__ float red[4][3];
  const int lane = t & 63, w = t >> 6;
  if (lane == 0) { red[w][0] = p_tt; red[w][1] = p_tb; red[w][2] = p_bb; }
  __syncthreads();
  const float s_tt = red[0][0] + red[1][0] + red[2][0] + red[3][0];
  const float s_tb = red[0][1] + red[1][1] + red[2][1] + red[3][1];
  const float s_bb = red[0][2] + red[1][2] + red[2][2] + red[3][2];
  const float tn = sqrtf(fmaxf(s_tt, EPS2));
  const float th = tanhf(tn / (1.0f + EPS));
  const float g = th / tn;
  const float rnorm = th * (sqrtf(s_tt) / tn);
  const float sr = (rnorm >= MAXN) ? (MAXN / (rnorm + EPS)) : 1.0f;
  const float gr = g * sr;
  const float rn = (rnorm * sr) * (rnorm * sr);
  const float bnorm = sqrtf(fmaxf(s_bb, EPS2));
  const float sb = (bnorm >= MAXN) ? (MAXN / (bnorm + EPS)) : 1.0f;
  const float xy = gr * sb * s_tb;
  const float yn = (sb * sb) * s_bb;
  const float Af = 1.0f + 2.0f * xy + yn;
  const float Cf = 1.0f - rn;
  const float den = 1.0f + 2.0f * xy + rn * yn + EPS;
  const float id = 1.0f / den;
  const float on_raw = (Af * Af * rn + 2.0f * Af * Cf * xy + Cf * Cf * yn) * (id * id);
  const float no = sqrtf(fmaxf(on_raw, EPS2));
  const float so = (no >= MAXN) ? (MAXN / (no + EPS)) : 1.0f;
  const float ms = id * so;
  const float ca = gr * Af * ms;
  const float cb = sb * Cf * ms;
  const float v0 = ca * tp.x + cb * bp.x;
  const float v1 = ca * tp.y + cb * bp.y;
  if (final_mode) {
    float2 o; o.x = v0; o.y = v1;
    *(float2*)&o0[(size_t)nrow * 512 + e0] = o;
    return;
  }
  float hp = v0 * v0 + v1 * v1;
#pragma unroll
  for (int m = 16; m; m >>= 1) hp += __shfl_xor(hp, m, 64);
  const float hnr = sqrtf(fmaxf(hp, EPS2));
  float sh = 1.0f;
  if (z != 2) sh = (hnr >= MAXN) ? (MAXN / (hnr + EPS)) : 1.0f;
  float* outz = (z == 0) ? o0 : ((z == 1) ? o1 : o2);
  float* nz = (z == 0) ? nrm0 : ((z == 1) ? nrm1 : nrm2);
  const int b = nrow >> 9, s = nrow & 511, h = e0 >> 6, d = e0 & 63;
  float2 o; o.x = v0 * sh; o.y = v1 * sh;
  *(float2*)&outz[(((size_t)(b * 8 + h) * 512 + s) * 64 + d)] = o;
  if ((t & 31) == 0) nz[(size_t)(b * 8 + h) * 512 + s] = hp * sh * sh;
  if (z == 0 && t < 8) rowsum_init[((size_t)(nrow >> 9) * 8 + t) * 512 + (nrow & 511)] = 0.0f;
}

// ---------- K4: r = exp(-dist) EXACTLY = 1/(z+sqrt(z^2-1)); row-sums via atomics ----------
__global__ __launch_bounds__(256) void k_logits(const float* __restrict__ Q,
                                                const float* __restrict__ K,
                                                const float* __restrict__ qn,
                                                const float* __restrict__ kn,
                                                float* __restrict__ attn,
                                                float* __restrict__ rowsum) {
  const int bh = blockIdx.z;
  const int i0 = blockIdx.x * 64;
  const int j0 = blockIdx.y * 128;
  const float* Qb = Q + (size_t)bh * 512 * 64;
  const float* Kb = K + (size_t)bh * 512 * 64;
  __shared__ __align__(16) float q_lds[64][68];
  __shared__ __align__(16) float k_lds[128][68];
  const int t = threadIdx.x;
  const int tx = t & 15, ty = t >> 4;
  const int tx4 = tx * 4;
#pragma unroll
  for (int it = 0; it < 4; ++it) {
    const int row = it * 16 + ty;
    *(float4*)&q_lds[row][tx4] = *(const float4*)&Qb[(size_t)(i0 + row) * 64 + tx4];
  }
#pragma unroll
  for (int it = 0; it < 8; ++it) {
    const int row = it * 16 + ty;
    *(float4*)&k_lds[row][tx4] = *(const float4*)&Kb[(size_t)(j0 + row) * 64 + tx4];
  }
  __syncthreads();
  float acc[4][8] = {};
#pragma unroll
  for (int d = 0; d < 64; d += 4) {
    float4 qv[4], kv[8];
#pragma unroll
    for (int i = 0; i < 4; ++i) qv[i] = *(const float4*)&q_lds[ty * 4 + i][d];
#pragma unroll
    for (int j = 0; j < 8; ++j) kv[j] = *(const float4*)&k_lds[tx + 16 * j][d];
#pragma unroll
    for (int i = 0; i < 4; ++i)
#pragma unroll
      for (int j = 0; j < 8; ++j) {
        acc[i][j] = fmaf(qv[i].x, kv[j].x, acc[i][j]);
        acc[i][j] = fmaf(qv[i].y, kv[j].y, acc[i][j]);
        acc[i][j] = fmaf(qv[i].z, kv[j].z, acc[i][j]);
        acc[i][j] = fmaf(qv[i].w, kv[j].w, acc[i][j]);
      }
  }
  float qni[4], knj[8];
#pragma unroll
  for (int i = 0; i < 4; ++i) qni[i] = qn[(size_t)bh * 512 + i0 + ty * 4 + i];
#pragma unroll
  for (int j = 0; j < 8; ++j) knj[j] = kn[(size_t)bh * 512 + j0 + tx + 16 * j];
  float rs_[4] = {};
#pragma unroll
  for (int i = 0; i < 4; ++i)
#pragma unroll
    for (int j = 0; j < 8; ++j) {
      const float num = fmaxf(qni[i] + knj[j] - 2.0f * acc[i][j], 0.0f);
      const float den = fmaxf((1.0f - qni[i]) * (1.0f - knj[j]), EPS);
      const float wv = 2.0f * num / den + EPS;
      const float s_ = 1.0f + wv + sqrtf(wv * (wv + 2.0f));
      const float r = __builtin_amdgcn_rcpf(s_);
      rs_[i] += r;
      attn[((size_t)bh * 512 + i0 + ty * 4 + i) * 512 + j0 + tx + 16 * j] = r;
    }
#pragma unroll
  for (int i = 0; i < 4; ++i) {
    float v = rs_[i];
    v += __shfl_xor(v, 1, 64); v += __shfl_xor(v, 2, 64);
    v += __shfl_xor(v, 4, 64); v += __shfl_xor(v, 8, 64);
    if (tx == 0) atomicAdd(&rowsum[(size_t)bh * 512 + i0 + ty * 4 + i], v);
  }
}

// ---------- K6 v7: mobius scan with norm-identity chain ----------
// |x (+) y|^2 * den = (xn + 2xy + yn) * (den - EPS)  [proved identity] ->
// xn' in 4 insts with a 2-deep post-rcp chain. Unroll 16 (I$-friendly).
__global__ __launch_bounds__(256) void k_scan(const float* __restrict__ V,
                                              const float* __restrict__ vn,
                                              const float* __restrict__ rw,
                                              const float* __restrict__ rowsum,
                                              float* __restrict__ att) {
  __shared__ __align__(16) float v_lds[64 * 64];
  __shared__ __align__(16) float swyn_lds[64 * 66];
  const int blk = blockIdx.x;
  const int bh = blk >> 4;
  const int i0 = (blk & 15) * 32;
  const int t = threadIdx.x;
  const int lane = t & 63, w = t >> 6;
  const int row_blk = w * 8 + (lane >> 3);
  const int sub = lane & 7;
  const int d0 = sub * 8;
  const float* Vb = V + (size_t)bh * 512 * 64;
  const float* vnb = vn + (size_t)bh * 512;
  const float* arow = rw + ((size_t)bh * 512 + i0 + row_blk) * 512;
  const float inv_s = __builtin_amdgcn_rcpf(rowsum[(size_t)bh * 512 + i0 + row_blk]);

  float ws[8];
#pragma unroll
  for (int k = 0; k < 8; ++k) ws[k] = 0.0f;
  float xn = 0.0f;

  for (int jc = 0; jc < 512; jc += 64) {
#pragma unroll
    for (int it = 0; it < 4; ++it) {
      const int idx4 = it * 256 + t;
      *(float4*)&v_lds[idx4 * 4] = *(const float4*)&Vb[(size_t)jc * 64 + idx4 * 4];
    }
    const float4 a0 = *(const float4*)&arow[jc + sub * 8];
    const float4 a1 = *(const float4*)&arow[jc + sub * 8 + 4];
    const float4 n0 = *(const float4*)&vnb[jc + sub * 8];
    const float4 n1 = *(const float4*)&vnb[jc + sub * 8 + 4];
    const float wq[8] = {a0.x, a0.y, a0.z, a0.w, a1.x, a1.y, a1.z, a1.w};
    const float nq[8] = {n0.x, n0.y, n0.z, n0.w, n1.x, n1.y, n1.z, n1.w};
#pragma unroll
    for (int e = 0; e < 8; ++e) {
      const float wgt = wq[e] * inv_s;
      float2 p; p.x = wgt; p.y = (wgt * wgt) * nq[e];
      *(float2*)&swyn_lds[(sub * 8 + e) * 66 + row_blk * 2] = p;
    }
    __syncthreads();

#pragma unroll 16
    for (int j = 0; j < 64; ++j) {
      const float2 sy2 = *(const float2*)&swyn_lds[j * 66 + row_blk * 2];
      const float4 v0 = *(const float4*)&v_lds[j * 64 + d0];
      const float4 v1 = *(const float4*)&v_lds[j * 64 + d0 + 4];
      const float sw = sy2.x, yn = sy2.y;
      // off-chain scalars (depend only on xn from prev step + LDS values)
      const float xnyn1 = fmaf(xn, yn, 1.0f + EPS);
      const float sxy   = xn + yn;
      const float ynp1  = 1.0f + yn;
      const float Cfsw  = (1.0f - xn) * sw;
      // dot(ws, v_j) across the 8-lane row
      float da = ws[0] * v0.x;
      da = fmaf(ws[1], v0.y, da); da = fmaf(ws[2], v0.z, da); da = fmaf(ws[3], v0.w, da);
      float db = ws[4] * v1.x;
      db = fmaf(ws[5], v1.y, db); db = fmaf(ws[6], v1.z, db); db = fmaf(ws[7], v1.w, db);
      float d = da + db;
      d += qperm<QP_XOR1>(d);
      d += qperm<QP_XOR2>(d);
      d += qperm<QP_HALFMIR>(d);
      const float xy  = sw * d;
      const float den = fmaf(2.0f, xy, xnyn1);
      const float s2  = fmaf(2.0f, xy, sxy);
      const float Af  = fmaf(2.0f, xy, ynp1);
      const float id  = __builtin_amdgcn_rcpf(den);
      const float dn  = den - EPS;
      const float am  = Af * id;
      const float cm  = Cfsw * id;
      const float xa  = s2 * id;
      const float xb  = dn * id;
      xn = xa * xb;                      // exact |ws'|^2 via norm identity
      ws[0] = fmaf(am, ws[0], cm * v0.x); ws[1] = fmaf(am, ws[1], cm * v0.y);
      ws[2] = fmaf(am, ws[2], cm * v0.z); ws[3] = fmaf(am, ws[3], cm * v0.w);
      ws[4] = fmaf(am, ws[4], cm * v1.x); ws[5] = fmaf(am, ws[5], cm * v1.y);
      ws[6] = fmaf(am, ws[6], cm * v1.z); ws[7] = fmaf(am, ws[7], cm * v1.w);
    }
    __syncthreads();
  }
  // write att in [B,S,E] row-major: row = b*512 + s, col = h*64 + d
  const int b = bh >> 3, h = bh & 7;
  float* o = att + (((size_t)b * 512 + i0 + row_blk) * 512 + h * 64 + d0);
  float4 s0; s0.x = ws[0]; s0.y = ws[1]; s0.z = ws[2]; s0.w = ws[3];
  float4 s1; s1.x = ws[4]; s1.y = ws[5]; s1.z = ws[6]; s1.w = ws[7];
  *(float4*)&o[0] = s0;
  *(float4*)&o[4] = s1;
}

extern "C" void kernel_launch(void* const* d_in, const int* in_sizes, int n_in,
                              void* d_out, int out_size, void* d_ws, size_t ws_size,
                              hipStream_t stream) {
  const float* query = (const float*)d_in[0];
  const float* key_  = (const float*)d_in[1];
  const float* value = (const float*)d_in[2];
  const float* Wq = (const float*)d_in[3];
  const float* bq = (const float*)d_in[4];
  const float* Wk = (const float*)d_in[5];
  const float* bk = (const float*)d_in[6];
  const float* Wv = (const float*)d_in[7];
  const float* bv = (const float*)d_in[8];
  const float* Wo = (const float*)d_in[9];
  const float* bo = (const float*)d_in[10];
  float* ws = (float*)d_ws;
  const size_t M = 1u << 20;            // 1M floats
  float* Qb     = ws;                   // [32,512,64]
  float* Kb     = ws + 1 * M;
  float* Vb     = ws + 2 * M;
  float* qn     = ws + 3 * M;           // [32,512]
  float* kn     = qn + 16384;
  float* vn     = kn + 16384;
  float* rowsum = vn + 16384;           // [32,512]
  float* rw     = ws + 4 * M;           // [32,512,512] unnormalized weights
  float* t3     = ws + 12 * M;          // 3x [2048,512]
  float* att    = ws + 15 * M;          // [2048,512] row-major [B,S,E]
  float* to_    = ws + 16 * M;          // [2048,512]

  k_gemm_mfma<<<dim3(32, 8, 3), 256, 0, stream>>>(query, key_, value, Wq, Wk, Wv, t3);
  k_post<<<dim3(2048, 3), 256, 0, stream>>>(t3, bq, bk, bv, Qb, Kb, Vb, qn, kn, vn,
                                            rowsum, 0);
  k_logits<<<dim3(8, 4, 32), 256, 0, stream>>>(Qb, Kb, qn, kn, rw, rowsum);
  k_scan<<<512, 256, 0, stream>>>(Vb, vn, rw, rowsum, att);
  k_gemm_mfma<<<dim3(32, 8, 1), 256, 0, stream>>>(att, att, att, Wo, Wo, Wo, to_);
  k_post<<<dim3(2048, 1), 256, 0, stream>>>(to_, bo, bo, bo, (float*)d_out,
                                            nullptr, nullptr, nullptr, nullptr, nullptr,
                                            nullptr, 1);
}

// Round 8
// 255.460 us; speedup vs baseline: 1.0936x; 1.0936x over previous
//
#include <hip/hip_runtime.h>
#include <math.h>

#define EPS  1e-5f
#define EPS2 1e-10f
#define MAXN (1.0f - EPS)

using short8  = __attribute__((ext_vector_type(8))) short;
using floatx4 = __attribute__((ext_vector_type(4))) float;

// DPP cross-lane: pure VALU, never touches the LDS pipe
template <int CTRL>
static __device__ __forceinline__ float qperm(float x) {
  return __int_as_float(__builtin_amdgcn_update_dpp(
      __float_as_int(x), __float_as_int(x), CTRL, 0xF, 0xF, false));
}
#define QP_XOR1    0xB1   // quad_perm [1,0,3,2]
#define QP_XOR2    0x4E   // quad_perm [2,3,0,1]
#define QP_HALFMIR 0x141  // row_half_mirror: lane -> lane^7 within 8

// RNE fp32 -> bf16 split helpers
static __device__ __forceinline__ short bf16_rne(float x) {
  unsigned u = __float_as_uint(x);
  unsigned r = u + 0x7FFFu + ((u >> 16) & 1u);
  return (short)(r >> 16);
}
static __device__ __forceinline__ float bf16_tof(short h) {
  return __uint_as_float(((unsigned)(unsigned short)h) << 16);
}

// logmap scale factor from row sumsq
static __device__ __forceinline__ float logmap_f(float ss) {
  const float r = sqrtf(fmaxf(ss, EPS2));
  float at;
  if (r >= MAXN) {
    at = 0.5f * logf((r * (2.0f - EPS) + EPS) / (EPS * (1.0f + r)));
  } else {
    at = 0.5f * logf((1.0f + r) / (1.0f - r));
  }
  return (1.0f + EPS) * at / r;
}

// ---------- K2: C = f[row]*(A @ W^T) via 3-term bf16-split MFMA ----------
__global__ __launch_bounds__(256) void k_gemm_mfma(
    const float* __restrict__ A0, const float* __restrict__ A1, const float* __restrict__ A2,
    const float* __restrict__ W0, const float* __restrict__ W1, const float* __restrict__ W2,
    float* __restrict__ Cbase) {
  const int z = blockIdx.z;
  const float* A = (z == 0) ? A0 : ((z == 1) ? A1 : A2);
  const float* W = (z == 0) ? W0 : ((z == 1) ? W1 : W2);
  float* C = Cbase + (size_t)z * (2048 * 512);
  __shared__ short Ahi[64][72], Alo[64][72], Whi[64][72], Wlo[64][72];
  __shared__ float f_lds[64];
  const int t = threadIdx.x;
  const int n0 = blockIdx.x * 64;   // M offset (rows, 2048)
  const int m0 = blockIdx.y * 64;   // N offset (cols, 512)
  const int row = t >> 2, c0 = (t & 3) * 16;
  const int w = t >> 6, lane = t & 63;
  const int quad = lane >> 4, l16 = lane & 15;
  const int mw = (w & 1) * 32, nw = (w >> 1) * 32;
  floatx4 acc[2][2];
#pragma unroll
  for (int i = 0; i < 2; ++i)
#pragma unroll
    for (int j = 0; j < 2; ++j) acc[i][j] = (floatx4){0.f, 0.f, 0.f, 0.f};
  float ssq = 0.0f;

  for (int k0 = 0; k0 < 512; k0 += 64) {
    float4 av[4], wv[4];
#pragma unroll
    for (int i = 0; i < 4; ++i) {
      av[i] = *(const float4*)&A[(size_t)(n0 + row) * 512 + k0 + c0 + 4 * i];
      wv[i] = *(const float4*)&W[(size_t)(m0 + row) * 512 + k0 + c0 + 4 * i];
    }
    __syncthreads();
#pragma unroll
    for (int i = 0; i < 4; ++i) {
      const float a4[4] = {av[i].x, av[i].y, av[i].z, av[i].w};
      const float w4[4] = {wv[i].x, wv[i].y, wv[i].z, wv[i].w};
#pragma unroll
      for (int e = 0; e < 4; ++e) {
        ssq = fmaf(a4[e], a4[e], ssq);
        const short ah = bf16_rne(a4[e]);
        const short wh = bf16_rne(w4[e]);
        Ahi[row][c0 + 4 * i + e] = ah;
        Alo[row][c0 + 4 * i + e] = bf16_rne(a4[e] - bf16_tof(ah));
        Whi[row][c0 + 4 * i + e] = wh;
        Wlo[row][c0 + 4 * i + e] = bf16_rne(w4[e] - bf16_tof(wh));
      }
    }
    __syncthreads();
#pragma unroll
    for (int kk = 0; kk < 64; kk += 32) {
      short8 ah[2], al[2], bh[2], bl[2];
#pragma unroll
      for (int i = 0; i < 2; ++i) {
        ah[i] = *(const short8*)&Ahi[mw + i * 16 + l16][kk + quad * 8];
        al[i] = *(const short8*)&Alo[mw + i * 16 + l16][kk + quad * 8];
        bh[i] = *(const short8*)&Whi[nw + i * 16 + l16][kk + quad * 8];
        bl[i] = *(const short8*)&Wlo[nw + i * 16 + l16][kk + quad * 8];
      }
#pragma unroll
      for (int i = 0; i < 2; ++i)
#pragma unroll
        for (int j = 0; j < 2; ++j) {
          acc[i][j] = __builtin_amdgcn_mfma_f32_16x16x32_bf16(ah[i], bh[j], acc[i][j], 0, 0, 0);
          acc[i][j] = __builtin_amdgcn_mfma_f32_16x16x32_bf16(ah[i], bl[j], acc[i][j], 0, 0, 0);
          acc[i][j] = __builtin_amdgcn_mfma_f32_16x16x32_bf16(al[i], bh[j], acc[i][j], 0, 0, 0);
        }
    }
  }
  // fused rownorm: threads 4r..4r+3 form a quad for row r
  ssq += qperm<QP_XOR1>(ssq);
  ssq += qperm<QP_XOR2>(ssq);
  if ((t & 3) == 0) f_lds[row] = logmap_f(ssq);
  __syncthreads();
#pragma unroll
  for (int i = 0; i < 2; ++i) {
    const int lrow_base = mw + i * 16 + quad * 4;
#pragma unroll
    for (int r = 0; r < 4; ++r) {
      const float fv = f_lds[lrow_base + r];
#pragma unroll
      for (int j = 0; j < 2; ++j)
        C[(size_t)(n0 + lrow_base + r) * 512 + m0 + nw + j * 16 + l16] = fv * acc[i][j][r];
    }
  }
}

// ---------- K3: expmap0 + mobius-add bias; per-head project + norms ----------
__global__ __launch_bounds__(256) void k_post(const float* __restrict__ tin,
                                              const float* __restrict__ b0,
                                              const float* __restrict__ b1,
                                              const float* __restrict__ b2,
                                              float* __restrict__ o0, float* __restrict__ o1,
                                              float* __restrict__ o2,
                                              float* __restrict__ nrm0, float* __restrict__ nrm1,
                                              float* __restrict__ nrm2,
                                              float* __restrict__ rowsum_init, int final_mode) {
  const int nrow = blockIdx.x, z = blockIdx.y, t = threadIdx.x;
  const float* tv = tin + ((size_t)z * 2048 + nrow) * 512;
  const float* bias = (z == 0) ? b0 : ((z == 1) ? b1 : b2);
  const int e0 = 2 * t;
  const float2 tp = *(const float2*)&tv[e0];
  const float2 bp = *(const float2*)&bias[e0];
  float p_tt = tp.x * tp.x + tp.y * tp.y;
  float p_tb = tp.x * bp.x + tp.y * bp.y;
  float p_bb = bp.x * bp.x + bp.y * bp.y;
#pragma unroll
  for (int m = 32; m; m >>= 1) {
    p_tt += __shfl_xor(p_tt, m, 64);
    p_tb += __shfl_xor(p_tb, m, 64);
    p_bb += __shfl_xor(p_bb, m, 64);
  }
  __shared__ float red[4][3];
  const int lane = t & 63, w = t >> 6;
  if (lane == 0) { red[w][0] = p_tt; red[w][1] = p_tb; red[w][2] = p_bb; }
  __syncthreads();
  const float s_tt = red[0][0] + red[1][0] + red[2][0] + red[3][0];
  const float s_tb = red[0][1] + red[1][1] + red[2][1] + red[3][1];
  const float s_bb = red[0][2] + red[1][2] + red[2][2] + red[3][2];
  const float tn = sqrtf(fmaxf(s_tt, EPS2));
  const float th = tanhf(tn / (1.0f + EPS));
  const float g = th / tn;
  const float rnorm = th * (sqrtf(s_tt) / tn);
  const float sr = (rnorm >= MAXN) ? (MAXN / (rnorm + EPS)) : 1.0f;
  const float gr = g * sr;
  const float rn = (rnorm * sr) * (rnorm * sr);
  const float bnorm = sqrtf(fmaxf(s_bb, EPS2));
  const float sb = (bnorm >= MAXN) ? (MAXN / (bnorm + EPS)) : 1.0f;
  const float xy = gr * sb * s_tb;
  const float yn = (sb * sb) * s_bb;
  const float Af = 1.0f + 2.0f * xy + yn;
  const float Cf = 1.0f - rn;
  const float den = 1.0f + 2.0f * xy + rn * yn + EPS;
  const float id = 1.0f / den;
  const float on_raw = (Af * Af * rn + 2.0f * Af * Cf * xy + Cf * Cf * yn) * (id * id);
  const float no = sqrtf(fmaxf(on_raw, EPS2));
  const float so = (no >= MAXN) ? (MAXN / (no + EPS)) : 1.0f;
  const float ms = id * so;
  const float ca = gr * Af * ms;
  const float cb = sb * Cf * ms;
  const float v0 = ca * tp.x + cb * bp.x;
  const float v1 = ca * tp.y + cb * bp.y;
  if (final_mode) {
    float2 o; o.x = v0; o.y = v1;
    *(float2*)&o0[(size_t)nrow * 512 + e0] = o;
    return;
  }
  float hp = v0 * v0 + v1 * v1;
#pragma unroll
  for (int m = 16; m; m >>= 1) hp += __shfl_xor(hp, m, 64);
  const float hnr = sqrtf(fmaxf(hp, EPS2));
  float sh = 1.0f;
  if (z != 2) sh = (hnr >= MAXN) ? (MAXN / (hnr + EPS)) : 1.0f;
  float* outz = (z == 0) ? o0 : ((z == 1) ? o1 : o2);
  float* nz = (z == 0) ? nrm0 : ((z == 1) ? nrm1 : nrm2);
  const int b = nrow >> 9, s = nrow & 511, h = e0 >> 6, d = e0 & 63;
  float2 o; o.x = v0 * sh; o.y = v1 * sh;
  *(float2*)&outz[(((size_t)(b * 8 + h) * 512 + s) * 64 + d)] = o;
  if ((t & 31) == 0) nz[(size_t)(b * 8 + h) * 512 + s] = hp * sh * sh;
  if (z == 0 && t < 8) rowsum_init[((size_t)(nrow >> 9) * 8 + t) * 512 + (nrow & 511)] = 0.0f;
}

// ---------- K4 v2: QK^T via bf16-split MFMA; r = exp(-dist) = rcp(z+sqrt(z^2-1)) ----------
__global__ __launch_bounds__(256) void k_logits(const float* __restrict__ Q,
                                                const float* __restrict__ K,
                                                const float* __restrict__ qn,
                                                const float* __restrict__ kn,
                                                float* __restrict__ attn,
                                                float* __restrict__ rowsum) {
  const int bh = blockIdx.z;
  const int i0 = blockIdx.x * 64;
  const int j0 = blockIdx.y * 64;
  const float* Qb = Q + (size_t)bh * 512 * 64;
  const float* Kb = K + (size_t)bh * 512 * 64;
  __shared__ short Qhi[64][72], Qlo[64][72], Khi[64][72], Klo[64][72];
  const int t = threadIdx.x;
  const int row = t >> 2, c0 = (t & 3) * 16;
  const int w = t >> 6, lane = t & 63;
  const int quad = lane >> 4, l16 = lane & 15;
  const int mw = (w & 1) * 32, nw = (w >> 1) * 32;
  // stage + split (K-dim = 64, single stage)
  float4 qv4[4], kv4[4];
#pragma unroll
  for (int i = 0; i < 4; ++i) {
    qv4[i] = *(const float4*)&Qb[(size_t)(i0 + row) * 64 + c0 + 4 * i];
    kv4[i] = *(const float4*)&Kb[(size_t)(j0 + row) * 64 + c0 + 4 * i];
  }
#pragma unroll
  for (int i = 0; i < 4; ++i) {
    const float q4[4] = {qv4[i].x, qv4[i].y, qv4[i].z, qv4[i].w};
    const float k4[4] = {kv4[i].x, kv4[i].y, kv4[i].z, kv4[i].w};
#pragma unroll
    for (int e = 0; e < 4; ++e) {
      const short qh = bf16_rne(q4[e]);
      const short kh = bf16_rne(k4[e]);
      Qhi[row][c0 + 4 * i + e] = qh;
      Qlo[row][c0 + 4 * i + e] = bf16_rne(q4[e] - bf16_tof(qh));
      Khi[row][c0 + 4 * i + e] = kh;
      Klo[row][c0 + 4 * i + e] = bf16_rne(k4[e] - bf16_tof(kh));
    }
  }
  __syncthreads();
  floatx4 acc[2][2];
#pragma unroll
  for (int i = 0; i < 2; ++i)
#pragma unroll
    for (int j = 0; j < 2; ++j) acc[i][j] = (floatx4){0.f, 0.f, 0.f, 0.f};
#pragma unroll
  for (int kk = 0; kk < 64; kk += 32) {
    short8 ah[2], al[2], bhv[2], blv[2];
#pragma unroll
    for (int i = 0; i < 2; ++i) {
      ah[i] = *(const short8*)&Qhi[mw + i * 16 + l16][kk + quad * 8];
      al[i] = *(const short8*)&Qlo[mw + i * 16 + l16][kk + quad * 8];
      bhv[i] = *(const short8*)&Khi[nw + i * 16 + l16][kk + quad * 8];
      blv[i] = *(const short8*)&Klo[nw + i * 16 + l16][kk + quad * 8];
    }
#pragma unroll
    for (int i = 0; i < 2; ++i)
#pragma unroll
      for (int j = 0; j < 2; ++j) {
        acc[i][j] = __builtin_amdgcn_mfma_f32_16x16x32_bf16(ah[i], bhv[j], acc[i][j], 0, 0, 0);
        acc[i][j] = __builtin_amdgcn_mfma_f32_16x16x32_bf16(ah[i], blv[j], acc[i][j], 0, 0, 0);
        acc[i][j] = __builtin_amdgcn_mfma_f32_16x16x32_bf16(al[i], bhv[j], acc[i][j], 0, 0, 0);
      }
  }
  // epilogue: weight + rowsum
#pragma unroll
  for (int i = 0; i < 2; ++i) {
    float rs_acc[4] = {0.f, 0.f, 0.f, 0.f};
#pragma unroll
    for (int r = 0; r < 4; ++r) {
      const int grow = i0 + mw + i * 16 + quad * 4 + r;
      const float qni = qn[(size_t)bh * 512 + grow];
      const float rq = 1.0f - qni;
#pragma unroll
      for (int j = 0; j < 2; ++j) {
        const int gcol = j0 + nw + j * 16 + l16;
        const float knj = kn[(size_t)bh * 512 + gcol];
        const float num = fmaxf(qni + knj - 2.0f * acc[i][j][r], 0.0f);
        const float den = fmaxf(rq * (1.0f - knj), EPS);
        const float wv = fmaf(2.0f * num, __builtin_amdgcn_rcpf(den), EPS);
        const float s_ = 1.0f + wv + sqrtf(wv * (wv + 2.0f));
        const float rr = __builtin_amdgcn_rcpf(s_);
        rs_acc[r] += rr;
        attn[((size_t)bh * 512 + grow) * 512 + gcol] = rr;
      }
    }
#pragma unroll
    for (int r = 0; r < 4; ++r) {
      float v = rs_acc[r];
      v += __shfl_xor(v, 1, 64); v += __shfl_xor(v, 2, 64);
      v += __shfl_xor(v, 4, 64); v += __shfl_xor(v, 8, 64);
      if (l16 == 0)
        atomicAdd(&rowsum[(size_t)bh * 512 + i0 + mw + i * 16 + quad * 4 + r], v);
    }
  }
}

// ---------- K6 v8: mobius scan, full unroll + norm-identity chain ----------
__global__ __launch_bounds__(256) void k_scan(const float* __restrict__ V,
                                              const float* __restrict__ vn,
                                              const float* __restrict__ rw,
                                              const float* __restrict__ rowsum,
                                              float* __restrict__ att) {
  __shared__ __align__(16) float v_lds[64 * 64];
  __shared__ __align__(16) float swyn_lds[64 * 66];
  const int blk = blockIdx.x;
  const int bh = blk >> 4;
  const int i0 = (blk & 15) * 32;
  const int t = threadIdx.x;
  const int lane = t & 63, w = t >> 6;
  const int row_blk = w * 8 + (lane >> 3);
  const int sub = lane & 7;
  const int d0 = sub * 8;
  const float* Vb = V + (size_t)bh * 512 * 64;
  const float* vnb = vn + (size_t)bh * 512;
  const float* arow = rw + ((size_t)bh * 512 + i0 + row_blk) * 512;
  const float inv_s = __builtin_amdgcn_rcpf(rowsum[(size_t)bh * 512 + i0 + row_blk]);

  float ws[8];
#pragma unroll
  for (int k = 0; k < 8; ++k) ws[k] = 0.0f;
  float xn = 0.0f;

  for (int jc = 0; jc < 512; jc += 64) {
#pragma unroll
    for (int it = 0; it < 4; ++it) {
      const int idx4 = it * 256 + t;
      *(float4*)&v_lds[idx4 * 4] = *(const float4*)&Vb[(size_t)jc * 64 + idx4 * 4];
    }
    const float4 a0 = *(const float4*)&arow[jc + sub * 8];
    const float4 a1 = *(const float4*)&arow[jc + sub * 8 + 4];
    const float4 n0 = *(const float4*)&vnb[jc + sub * 8];
    const float4 n1 = *(const float4*)&vnb[jc + sub * 8 + 4];
    const float wq[8] = {a0.x, a0.y, a0.z, a0.w, a1.x, a1.y, a1.z, a1.w};
    const float nq[8] = {n0.x, n0.y, n0.z, n0.w, n1.x, n1.y, n1.z, n1.w};
#pragma unroll
    for (int e = 0; e < 8; ++e) {
      const float wgt = wq[e] * inv_s;
      float2 p; p.x = wgt; p.y = (wgt * wgt) * nq[e];
      *(float2*)&swyn_lds[(sub * 8 + e) * 66 + row_blk * 2] = p;
    }
    __syncthreads();

#pragma unroll
    for (int j = 0; j < 64; ++j) {
      const float2 sy2 = *(const float2*)&swyn_lds[j * 66 + row_blk * 2];
      const float4 v0 = *(const float4*)&v_lds[j * 64 + d0];
      const float4 v1 = *(const float4*)&v_lds[j * 64 + d0 + 4];
      const float sw = sy2.x, yn = sy2.y;
      // off-chain scalars (depend only on prev xn + LDS values)
      const float xnyn1 = fmaf(xn, yn, 1.0f + EPS);
      const float sxy   = xn + yn;
      const float ynp1  = 1.0f + yn;
      const float Cfsw  = (1.0f - xn) * sw;
      // dot(ws, v_j) across the 8-lane row
      float da = ws[0] * v0.x;
      da = fmaf(ws[1], v0.y, da); da = fmaf(ws[2], v0.z, da); da = fmaf(ws[3], v0.w, da);
      float db = ws[4] * v1.x;
      db = fmaf(ws[5], v1.y, db); db = fmaf(ws[6], v1.z, db); db = fmaf(ws[7], v1.w, db);
      float d = da + db;
      d += qperm<QP_XOR1>(d);
      d += qperm<QP_XOR2>(d);
      d += qperm<QP_HALFMIR>(d);
      const float xy  = sw * d;
      const float den = fmaf(2.0f, xy, xnyn1);
      const float s2  = fmaf(2.0f, xy, sxy);
      const float Af  = fmaf(2.0f, xy, ynp1);
      const float id  = __builtin_amdgcn_rcpf(den);
      const float dn  = den - EPS;
      const float am  = Af * id;
      const float cm  = Cfsw * id;
      const float xa  = s2 * id;
      const float xb  = dn * id;
      xn = xa * xb;                      // exact |ws'|^2 via norm identity
      ws[0] = fmaf(am, ws[0], cm * v0.x); ws[1] = fmaf(am, ws[1], cm * v0.y);
      ws[2] = fmaf(am, ws[2], cm * v0.z); ws[3] = fmaf(am, ws[3], cm * v0.w);
      ws[4] = fmaf(am, ws[4], cm * v1.x); ws[5] = fmaf(am, ws[5], cm * v1.y);
      ws[6] = fmaf(am, ws[6], cm * v1.z); ws[7] = fmaf(am, ws[7], cm * v1.w);
    }
    __syncthreads();
  }
  // write att in [B,S,E] row-major: row = b*512 + s, col = h*64 + d
  const int b = bh >> 3, h = bh & 7;
  float* o = att + (((size_t)b * 512 + i0 + row_blk) * 512 + h * 64 + d0);
  float4 s0; s0.x = ws[0]; s0.y = ws[1]; s0.z = ws[2]; s0.w = ws[3];
  float4 s1; s1.x = ws[4]; s1.y = ws[5]; s1.z = ws[6]; s1.w = ws[7];
  *(float4*)&o[0] = s0;
  *(float4*)&o[4] = s1;
}

extern "C" void kernel_launch(void* const* d_in, const int* in_sizes, int n_in,
                              void* d_out, int out_size, void* d_ws, size_t ws_size,
                              hipStream_t stream) {
  const float* query = (const float*)d_in[0];
  const float* key_  = (const float*)d_in[1];
  const float* value = (const float*)d_in[2];
  const float* Wq = (const float*)d_in[3];
  const float* bq = (const float*)d_in[4];
  const float* Wk = (const float*)d_in[5];
  const float* bk = (const float*)d_in[6];
  const float* Wv = (const float*)d_in[7];
  const float* bv = (const float*)d_in[8];
  const float* Wo = (const float*)d_in[9];
  const float* bo = (const float*)d_in[10];
  float* ws = (float*)d_ws;
  const size_t M = 1u << 20;            // 1M floats
  float* Qb     = ws;                   // [32,512,64]
  float* Kb     = ws + 1 * M;
  float* Vb     = ws + 2 * M;
  float* qn     = ws + 3 * M;           // [32,512]
  float* kn     = qn + 16384;
  float* vn     = kn + 16384;
  float* rowsum = vn + 16384;           // [32,512]
  float* rw     = ws + 4 * M;           // [32,512,512] unnormalized weights
  float* t3     = ws + 12 * M;          // 3x [2048,512]
  float* att    = ws + 15 * M;          // [2048,512] row-major [B,S,E]
  float* to_    = ws + 16 * M;          // [2048,512]

  k_gemm_mfma<<<dim3(32, 8, 3), 256, 0, stream>>>(query, key_, value, Wq, Wk, Wv, t3);
  k_post<<<dim3(2048, 3), 256, 0, stream>>>(t3, bq, bk, bv, Qb, Kb, Vb, qn, kn, vn,
                                            rowsum, 0);
  k_logits<<<dim3(8, 8, 32), 256, 0, stream>>>(Qb, Kb, qn, kn, rw, rowsum);
  k_scan<<<512, 256, 0, stream>>>(Vb, vn, rw, rowsum, att);
  k_gemm_mfma<<<dim3(32, 8, 1), 256, 0, stream>>>(att, att, att, Wo, Wo, Wo, to_);
  k_post<<<dim3(2048, 1), 256, 0, stream>>>(to_, bo, bo, bo, (float*)d_out,
                                            nullptr, nullptr, nullptr, nullptr, nullptr,
                                            nullptr, 1);
}

// Round 9
// 229.864 us; speedup vs baseline: 1.2153x; 1.1114x over previous
//
#include <hip/hip_runtime.h>
#include <math.h>

#define EPS  1e-5f
#define EPS2 1e-10f
#define MAXN (1.0f - EPS)

using short8  = __attribute__((ext_vector_type(8))) short;
using floatx4 = __attribute__((ext_vector_type(4))) float;
using float2v = __attribute__((ext_vector_type(2))) float;

// DPP cross-lane: pure VALU, never touches the LDS pipe
template <int CTRL>
static __device__ __forceinline__ float qperm(float x) {
  return __int_as_float(__builtin_amdgcn_update_dpp(
      __float_as_int(x), __float_as_int(x), CTRL, 0xF, 0xF, false));
}
#define QP_XOR1    0xB1   // quad_perm [1,0,3,2]
#define QP_XOR2    0x4E   // quad_perm [2,3,0,1]
#define QP_HALFMIR 0x141  // row_half_mirror: lane -> lane^7 within 8

// packed fp32 fma (v_pk_fma_f32 on CDNA)
#if __has_builtin(__builtin_elementwise_fma)
static __device__ __forceinline__ float2v fma2(float2v a, float2v b, float2v c) {
  return __builtin_elementwise_fma(a, b, c);
}
#else
static __device__ __forceinline__ float2v fma2(float2v a, float2v b, float2v c) {
  float2v r; r.x = fmaf(a.x, b.x, c.x); r.y = fmaf(a.y, b.y, c.y); return r;
}
#endif

// truncation bf16 split, pair-packed: low short = element a, high short = element b
static __device__ __forceinline__ int pack_hi2(float a, float b) {
  return (int)((__float_as_uint(a) >> 16) | (__float_as_uint(b) & 0xFFFF0000u));
}
static __device__ __forceinline__ float hi_of(float a) {
  return __uint_as_float(__float_as_uint(a) & 0xFFFF0000u);
}

// logmap scale factor from row sumsq
static __device__ __forceinline__ float logmap_f(float ss) {
  const float r = sqrtf(fmaxf(ss, EPS2));
  float at;
  if (r >= MAXN) {
    at = 0.5f * logf((r * (2.0f - EPS) + EPS) / (EPS * (1.0f + r)));
  } else {
    at = 0.5f * logf((1.0f + r) / (1.0f - r));
  }
  return (1.0f + EPS) * at / r;
}

// ---------- K2: C = f[row]*(A @ W^T) via 3-term bf16-split MFMA ----------
__global__ __launch_bounds__(256) void k_gemm_mfma(
    const float* __restrict__ A0, const float* __restrict__ A1, const float* __restrict__ A2,
    const float* __restrict__ W0, const float* __restrict__ W1, const float* __restrict__ W2,
    float* __restrict__ Cbase) {
  const int z = blockIdx.z;
  const float* A = (z == 0) ? A0 : ((z == 1) ? A1 : A2);
  const float* W = (z == 0) ? W0 : ((z == 1) ? W1 : W2);
  float* C = Cbase + (size_t)z * (2048 * 512);
  __shared__ int Ahi[64][36], Alo[64][36], Whi[64][36], Wlo[64][36];
  __shared__ float f_lds[64];
  const int t = threadIdx.x;
  const int n0 = blockIdx.x * 64;   // M offset
  const int m0 = blockIdx.y * 64;   // N offset
  const int row = t >> 2, c0 = (t & 3) * 16, ci = (t & 3) * 8;
  const int w = t >> 6, lane = t & 63;
  const int quad = lane >> 4, l16 = lane & 15;
  const int mw = (w & 1) * 32, nw = (w >> 1) * 32;
  floatx4 acc[2][2];
#pragma unroll
  for (int i = 0; i < 2; ++i)
#pragma unroll
    for (int j = 0; j < 2; ++j) acc[i][j] = (floatx4){0.f, 0.f, 0.f, 0.f};
  float ssq = 0.0f;

  for (int k0 = 0; k0 < 512; k0 += 64) {
    float4 av[4], wv[4];
#pragma unroll
    for (int i = 0; i < 4; ++i) {
      av[i] = *(const float4*)&A[(size_t)(n0 + row) * 512 + k0 + c0 + 4 * i];
      wv[i] = *(const float4*)&W[(size_t)(m0 + row) * 512 + k0 + c0 + 4 * i];
    }
    int pAh[8], pAl[8], pWh[8], pWl[8];
#pragma unroll
    for (int i = 0; i < 4; ++i) {
      ssq = fmaf(av[i].x, av[i].x, ssq); ssq = fmaf(av[i].y, av[i].y, ssq);
      ssq = fmaf(av[i].z, av[i].z, ssq); ssq = fmaf(av[i].w, av[i].w, ssq);
      pAh[2 * i]     = pack_hi2(av[i].x, av[i].y);
      pAh[2 * i + 1] = pack_hi2(av[i].z, av[i].w);
      pAl[2 * i]     = pack_hi2(av[i].x - hi_of(av[i].x), av[i].y - hi_of(av[i].y));
      pAl[2 * i + 1] = pack_hi2(av[i].z - hi_of(av[i].z), av[i].w - hi_of(av[i].w));
      pWh[2 * i]     = pack_hi2(wv[i].x, wv[i].y);
      pWh[2 * i + 1] = pack_hi2(wv[i].z, wv[i].w);
      pWl[2 * i]     = pack_hi2(wv[i].x - hi_of(wv[i].x), wv[i].y - hi_of(wv[i].y));
      pWl[2 * i + 1] = pack_hi2(wv[i].z - hi_of(wv[i].z), wv[i].w - hi_of(wv[i].w));
    }
    __syncthreads();
    *(int4*)&Ahi[row][ci]     = *(int4*)&pAh[0];
    *(int4*)&Ahi[row][ci + 4] = *(int4*)&pAh[4];
    *(int4*)&Alo[row][ci]     = *(int4*)&pAl[0];
    *(int4*)&Alo[row][ci + 4] = *(int4*)&pAl[4];
    *(int4*)&Whi[row][ci]     = *(int4*)&pWh[0];
    *(int4*)&Whi[row][ci + 4] = *(int4*)&pWh[4];
    *(int4*)&Wlo[row][ci]     = *(int4*)&pWl[0];
    *(int4*)&Wlo[row][ci + 4] = *(int4*)&pWl[4];
    __syncthreads();
#pragma unroll
    for (int kk = 0; kk < 64; kk += 32) {
      short8 ah[2], al[2], bh[2], bl[2];
#pragma unroll
      for (int i = 0; i < 2; ++i) {
        ah[i] = *(const short8*)&((const short*)Ahi[mw + i * 16 + l16])[kk + quad * 8];
        al[i] = *(const short8*)&((const short*)Alo[mw + i * 16 + l16])[kk + quad * 8];
        bh[i] = *(const short8*)&((const short*)Whi[nw + i * 16 + l16])[kk + quad * 8];
        bl[i] = *(const short8*)&((const short*)Wlo[nw + i * 16 + l16])[kk + quad * 8];
      }
#pragma unroll
      for (int i = 0; i < 2; ++i)
#pragma unroll
        for (int j = 0; j < 2; ++j) {
          acc[i][j] = __builtin_amdgcn_mfma_f32_16x16x32_bf16(ah[i], bh[j], acc[i][j], 0, 0, 0);
          acc[i][j] = __builtin_amdgcn_mfma_f32_16x16x32_bf16(ah[i], bl[j], acc[i][j], 0, 0, 0);
          acc[i][j] = __builtin_amdgcn_mfma_f32_16x16x32_bf16(al[i], bh[j], acc[i][j], 0, 0, 0);
        }
    }
  }
  // fused rownorm: threads 4r..4r+3 form a quad for row r
  ssq += qperm<QP_XOR1>(ssq);
  ssq += qperm<QP_XOR2>(ssq);
  if ((t & 3) == 0) f_lds[row] = logmap_f(ssq);
  __syncthreads();
#pragma unroll
  for (int i = 0; i < 2; ++i) {
    const int lrow_base = mw + i * 16 + quad * 4;
#pragma unroll
    for (int r = 0; r < 4; ++r) {
      const float fv = f_lds[lrow_base + r];
#pragma unroll
      for (int j = 0; j < 2; ++j)
        C[(size_t)(n0 + lrow_base + r) * 512 + m0 + nw + j * 16 + l16] = fv * acc[i][j][r];
    }
  }
}

// ---------- K3: expmap0 + mobius-add bias; per-head project + norms ----------
__global__ __launch_bounds__(256) void k_post(const float* __restrict__ tin,
                                              const float* __restrict__ b0,
                                              const float* __restrict__ b1,
                                              const float* __restrict__ b2,
                                              float* __restrict__ o0, float* __restrict__ o1,
                                              float* __restrict__ o2,
                                              float* __restrict__ nrm0, float* __restrict__ nrm1,
                                              float* __restrict__ nrm2,
                                              float* __restrict__ rowsum_init, int final_mode) {
  const int nrow = blockIdx.x, z = blockIdx.y, t = threadIdx.x;
  const float* tv = tin + ((size_t)z * 2048 + nrow) * 512;
  const float* bias = (z == 0) ? b0 : ((z == 1) ? b1 : b2);
  const int e0 = 2 * t;
  const float2 tp = *(const float2*)&tv[e0];
  const float2 bp = *(const float2*)&bias[e0];
  float p_tt = tp.x * tp.x + tp.y * tp.y;
  float p_tb = tp.x * bp.x + tp.y * bp.y;
  float p_bb = bp.x * bp.x + bp.y * bp.y;
#pragma unroll
  for (int m = 32; m; m >>= 1) {
    p_tt += __shfl_xor(p_tt, m, 64);
    p_tb += __shfl_xor(p_tb, m, 64);
    p_bb += __shfl_xor(p_bb, m, 64);
  }
  __shared__ float red[4][3];
  const int lane = t & 63, w = t >> 6;
  if (lane == 0) { red[w][0] = p_tt; red[w][1] = p_tb; red[w][2] = p_bb; }
  __syncthreads();
  const float s_tt = red[0][0] + red[1][0] + red[2][0] + red[3][0];
  const float s_tb = red[0][1] + red[1][1] + red[2][1] + red[3][1];
  const float s_bb = red[0][2] + red[1][2] + red[2][2] + red[3][2];
  const float tn = sqrtf(fmaxf(s_tt, EPS2));
  const float th = tanhf(tn / (1.0f + EPS));
  const float g = th / tn;
  const float rnorm = th * (sqrtf(s_tt) / tn);
  const float sr = (rnorm >= MAXN) ? (MAXN / (rnorm + EPS)) : 1.0f;
  const float gr = g * sr;
  const float rn = (rnorm * sr) * (rnorm * sr);
  const float bnorm = sqrtf(fmaxf(s_bb, EPS2));
  const float sb = (bnorm >= MAXN) ? (MAXN / (bnorm + EPS)) : 1.0f;
  const float xy = gr * sb * s_tb;
  const float yn = (sb * sb) * s_bb;
  const float Af = 1.0f + 2.0f * xy + yn;
  const float Cf = 1.0f - rn;
  const float den = 1.0f + 2.0f * xy + rn * yn + EPS;
  const float id = 1.0f / den;
  const float on_raw = (Af * Af * rn + 2.0f * Af * Cf * xy + Cf * Cf * yn) * (id * id);
  const float no = sqrtf(fmaxf(on_raw, EPS2));
  const float so = (no >= MAXN) ? (MAXN / (no + EPS)) : 1.0f;
  const float ms = id * so;
  const float ca = gr * Af * ms;
  const float cb = sb * Cf * ms;
  const float v0 = ca * tp.x + cb * bp.x;
  const float v1 = ca * tp.y + cb * bp.y;
  if (final_mode) {
    float2 o; o.x = v0; o.y = v1;
    *(float2*)&o0[(size_t)nrow * 512 + e0] = o;
    return;
  }
  float hp = v0 * v0 + v1 * v1;
#pragma unroll
  for (int m = 16; m; m >>= 1) hp += __shfl_xor(hp, m, 64);
  const float hnr = sqrtf(fmaxf(hp, EPS2));
  float sh = 1.0f;
  if (z != 2) sh = (hnr >= MAXN) ? (MAXN / (hnr + EPS)) : 1.0f;
  float* outz = (z == 0) ? o0 : ((z == 1) ? o1 : o2);
  float* nz = (z == 0) ? nrm0 : ((z == 1) ? nrm1 : nrm2);
  const int b = nrow >> 9, s = nrow & 511, h = e0 >> 6, d = e0 & 63;
  float2 o; o.x = v0 * sh; o.y = v1 * sh;
  *(float2*)&outz[(((size_t)(b * 8 + h) * 512 + s) * 64 + d)] = o;
  if ((t & 31) == 0) nz[(size_t)(b * 8 + h) * 512 + s] = hp * sh * sh;
  if (z == 0 && t < 8) rowsum_init[((size_t)(nrow >> 9) * 8 + t) * 512 + (nrow & 511)] = 0.0f;
}

// ---------- K4: QK^T via bf16-split MFMA; r = exp(-dist) = rcp(z+sqrt(z^2-1)) ----------
__global__ __launch_bounds__(256) void k_logits(const float* __restrict__ Q,
                                                const float* __restrict__ K,
                                                const float* __restrict__ qn,
                                                const float* __restrict__ kn,
                                                float* __restrict__ attn,
                                                float* __restrict__ rowsum) {
  const int bh = blockIdx.z;
  const int i0 = blockIdx.x * 64;
  const int j0 = blockIdx.y * 64;
  const float* Qb = Q + (size_t)bh * 512 * 64;
  const float* Kb = K + (size_t)bh * 512 * 64;
  __shared__ int Qhi[64][36], Qlo[64][36], Khi[64][36], Klo[64][36];
  const int t = threadIdx.x;
  const int row = t >> 2, c0 = (t & 3) * 16, ci = (t & 3) * 8;
  const int w = t >> 6, lane = t & 63;
  const int quad = lane >> 4, l16 = lane & 15;
  const int mw = (w & 1) * 32, nw = (w >> 1) * 32;
  float4 qv4[4], kv4[4];
#pragma unroll
  for (int i = 0; i < 4; ++i) {
    qv4[i] = *(const float4*)&Qb[(size_t)(i0 + row) * 64 + c0 + 4 * i];
    kv4[i] = *(const float4*)&Kb[(size_t)(j0 + row) * 64 + c0 + 4 * i];
  }
  int pQh[8], pQl[8], pKh[8], pKl[8];
#pragma unroll
  for (int i = 0; i < 4; ++i) {
    pQh[2 * i]     = pack_hi2(qv4[i].x, qv4[i].y);
    pQh[2 * i + 1] = pack_hi2(qv4[i].z, qv4[i].w);
    pQl[2 * i]     = pack_hi2(qv4[i].x - hi_of(qv4[i].x), qv4[i].y - hi_of(qv4[i].y));
    pQl[2 * i + 1] = pack_hi2(qv4[i].z - hi_of(qv4[i].z), qv4[i].w - hi_of(qv4[i].w));
    pKh[2 * i]     = pack_hi2(kv4[i].x, kv4[i].y);
    pKh[2 * i + 1] = pack_hi2(kv4[i].z, kv4[i].w);
    pKl[2 * i]     = pack_hi2(kv4[i].x - hi_of(kv4[i].x), kv4[i].y - hi_of(kv4[i].y));
    pKl[2 * i + 1] = pack_hi2(kv4[i].z - hi_of(kv4[i].z), kv4[i].w - hi_of(kv4[i].w));
  }
  *(int4*)&Qhi[row][ci]     = *(int4*)&pQh[0];
  *(int4*)&Qhi[row][ci + 4] = *(int4*)&pQh[4];
  *(int4*)&Qlo[row][ci]     = *(int4*)&pQl[0];
  *(int4*)&Qlo[row][ci + 4] = *(int4*)&pQl[4];
  *(int4*)&Khi[row][ci]     = *(int4*)&pKh[0];
  *(int4*)&Khi[row][ci + 4] = *(int4*)&pKh[4];
  *(int4*)&Klo[row][ci]     = *(int4*)&pKl[0];
  *(int4*)&Klo[row][ci + 4] = *(int4*)&pKl[4];
  __syncthreads();
  floatx4 acc[2][2];
#pragma unroll
  for (int i = 0; i < 2; ++i)
#pragma unroll
    for (int j = 0; j < 2; ++j) acc[i][j] = (floatx4){0.f, 0.f, 0.f, 0.f};
#pragma unroll
  for (int kk = 0; kk < 64; kk += 32) {
    short8 ah[2], al[2], bhv[2], blv[2];
#pragma unroll
    for (int i = 0; i < 2; ++i) {
      ah[i]  = *(const short8*)&((const short*)Qhi[mw + i * 16 + l16])[kk + quad * 8];
      al[i]  = *(const short8*)&((const short*)Qlo[mw + i * 16 + l16])[kk + quad * 8];
      bhv[i] = *(const short8*)&((const short*)Khi[nw + i * 16 + l16])[kk + quad * 8];
      blv[i] = *(const short8*)&((const short*)Klo[nw + i * 16 + l16])[kk + quad * 8];
    }
#pragma unroll
    for (int i = 0; i < 2; ++i)
#pragma unroll
      for (int j = 0; j < 2; ++j) {
        acc[i][j] = __builtin_amdgcn_mfma_f32_16x16x32_bf16(ah[i], bhv[j], acc[i][j], 0, 0, 0);
        acc[i][j] = __builtin_amdgcn_mfma_f32_16x16x32_bf16(ah[i], blv[j], acc[i][j], 0, 0, 0);
        acc[i][j] = __builtin_amdgcn_mfma_f32_16x16x32_bf16(al[i], bhv[j], acc[i][j], 0, 0, 0);
      }
  }
#pragma unroll
  for (int i = 0; i < 2; ++i) {
    float rs_acc[4] = {0.f, 0.f, 0.f, 0.f};
#pragma unroll
    for (int r = 0; r < 4; ++r) {
      const int grow = i0 + mw + i * 16 + quad * 4 + r;
      const float qni = qn[(size_t)bh * 512 + grow];
      const float rq = 1.0f - qni;
#pragma unroll
      for (int j = 0; j < 2; ++j) {
        const int gcol = j0 + nw + j * 16 + l16;
        const float knj = kn[(size_t)bh * 512 + gcol];
        const float num = fmaxf(qni + knj - 2.0f * acc[i][j][r], 0.0f);
        const float den = fmaxf(rq * (1.0f - knj), EPS);
        const float wv = fmaf(2.0f * num, __builtin_amdgcn_rcpf(den), EPS);
        const float s_ = 1.0f + wv + sqrtf(wv * (wv + 2.0f));
        const float rr = __builtin_amdgcn_rcpf(s_);
        rs_acc[r] += rr;
        attn[((size_t)bh * 512 + grow) * 512 + gcol] = rr;
      }
    }
#pragma unroll
    for (int r = 0; r < 4; ++r) {
      float v = rs_acc[r];
      v += __shfl_xor(v, 1, 64); v += __shfl_xor(v, 2, 64);
      v += __shfl_xor(v, 4, 64); v += __shfl_xor(v, 8, 64);
      if (l16 == 0)
        atomicAdd(&rowsum[(size_t)bh * 512 + i0 + mw + i * 16 + quad * 4 + r], v);
    }
  }
}

// ---------- K6 v9: mobius scan, full unroll + identity chain + packed fp32 ----------
__global__ __launch_bounds__(256) void k_scan(const float* __restrict__ V,
                                              const float* __restrict__ vn,
                                              const float* __restrict__ rw,
                                              const float* __restrict__ rowsum,
                                              float* __restrict__ att) {
  __shared__ __align__(16) float v_lds[64 * 64];
  __shared__ __align__(16) float swyn_lds[64 * 66];
  const int blk = blockIdx.x;
  const int bh = blk >> 4;
  const int i0 = (blk & 15) * 32;
  const int t = threadIdx.x;
  const int lane = t & 63, w = t >> 6;
  const int row_blk = w * 8 + (lane >> 3);
  const int sub = lane & 7;
  const int d0 = sub * 8;
  const float* Vb = V + (size_t)bh * 512 * 64;
  const float* vnb = vn + (size_t)bh * 512;
  const float* arow = rw + ((size_t)bh * 512 + i0 + row_blk) * 512;
  const float inv_s = __builtin_amdgcn_rcpf(rowsum[(size_t)bh * 512 + i0 + row_blk]);

  float2v wsv[4];
#pragma unroll
  for (int k = 0; k < 4; ++k) wsv[k] = (float2v){0.f, 0.f};
  float xn = 0.0f;

  for (int jc = 0; jc < 512; jc += 64) {
#pragma unroll
    for (int it = 0; it < 4; ++it) {
      const int idx4 = it * 256 + t;
      *(float4*)&v_lds[idx4 * 4] = *(const float4*)&Vb[(size_t)jc * 64 + idx4 * 4];
    }
    const float4 a0 = *(const float4*)&arow[jc + sub * 8];
    const float4 a1 = *(const float4*)&arow[jc + sub * 8 + 4];
    const float4 n0 = *(const float4*)&vnb[jc + sub * 8];
    const float4 n1 = *(const float4*)&vnb[jc + sub * 8 + 4];
    const float wq[8] = {a0.x, a0.y, a0.z, a0.w, a1.x, a1.y, a1.z, a1.w};
    const float nq[8] = {n0.x, n0.y, n0.z, n0.w, n1.x, n1.y, n1.z, n1.w};
#pragma unroll
    for (int e = 0; e < 8; ++e) {
      const float wgt = wq[e] * inv_s;
      float2 p; p.x = wgt; p.y = (wgt * wgt) * nq[e];
      *(float2*)&swyn_lds[(sub * 8 + e) * 66 + row_blk * 2] = p;
    }
    __syncthreads();

#pragma unroll
    for (int j = 0; j < 64; ++j) {
      const float2 sy2 = *(const float2*)&swyn_lds[j * 66 + row_blk * 2];
      const float4 v0 = *(const float4*)&v_lds[j * 64 + d0];
      const float4 v1 = *(const float4*)&v_lds[j * 64 + d0 + 4];
      const float2v vv0 = {v0.x, v0.y}, vv1 = {v0.z, v0.w};
      const float2v vv2 = {v1.x, v1.y}, vv3 = {v1.z, v1.w};
      const float sw = sy2.x, yn = sy2.y;
      // off-chain scalars (depend only on prev xn + LDS values)
      const float xnyn1 = fmaf(xn, yn, 1.0f + EPS);
      const float sxy   = xn + yn;
      const float ynp1  = 1.0f + yn;
      const float Cfsw  = (1.0f - xn) * sw;
      // dot(ws, v_j): packed fp32, 2 chains
      float2v da = wsv[0] * vv0;
      da = fma2(wsv[1], vv1, da);
      float2v db = wsv[2] * vv2;
      db = fma2(wsv[3], vv3, db);
      const float2v sv = da + db;
      float d = sv.x + sv.y;
      d += qperm<QP_XOR1>(d);
      d += qperm<QP_XOR2>(d);
      d += qperm<QP_HALFMIR>(d);
      const float xy  = sw * d;
      const float den = fmaf(2.0f, xy, xnyn1);
      const float s2  = fmaf(2.0f, xy, sxy);
      const float Af  = fmaf(2.0f, xy, ynp1);
      const float id  = __builtin_amdgcn_rcpf(den);
      const float dn  = den - EPS;
      const float am  = Af * id;
      const float cm  = Cfsw * id;
      xn = (s2 * id) * (dn * id);        // exact |ws'|^2 via norm identity
      const float2v amv = {am, am};
      const float2v cmv = {cm, cm};
      wsv[0] = fma2(amv, wsv[0], cmv * vv0);
      wsv[1] = fma2(amv, wsv[1], cmv * vv1);
      wsv[2] = fma2(amv, wsv[2], cmv * vv2);
      wsv[3] = fma2(amv, wsv[3], cmv * vv3);
    }
    __syncthreads();
  }
  // write att in [B,S,E] row-major: row = b*512 + s, col = h*64 + d
  const int b = bh >> 3, h = bh & 7;
  float* o = att + (((size_t)b * 512 + i0 + row_blk) * 512 + h * 64 + d0);
  float4 s0; s0.x = wsv[0].x; s0.y = wsv[0].y; s0.z = wsv[1].x; s0.w = wsv[1].y;
  float4 s1; s1.x = wsv[2].x; s1.y = wsv[2].y; s1.z = wsv[3].x; s1.w = wsv[3].y;
  *(float4*)&o[0] = s0;
  *(float4*)&o[4] = s1;
}

extern "C" void kernel_launch(void* const* d_in, const int* in_sizes, int n_in,
                              void* d_out, int out_size, void* d_ws, size_t ws_size,
                              hipStream_t stream) {
  const float* query = (const float*)d_in[0];
  const float* key_  = (const float*)d_in[1];
  const float* value = (const float*)d_in[2];
  const float* Wq = (const float*)d_in[3];
  const float* bq = (const float*)d_in[4];
  const float* Wk = (const float*)d_in[5];
  const float* bk = (const float*)d_in[6];
  const float* Wv = (const float*)d_in[7];
  const float* bv = (const float*)d_in[8];
  const float* Wo = (const float*)d_in[9];
  const float* bo = (const float*)d_in[10];
  float* ws = (float*)d_ws;
  const size_t M = 1u << 20;            // 1M floats
  float* Qb     = ws;                   // [32,512,64]
  float* Kb     = ws + 1 * M;
  float* Vb     = ws + 2 * M;
  float* qn     = ws + 3 * M;           // [32,512]
  float* kn     = qn + 16384;
  float* vn     = kn + 16384;
  float* rowsum = vn + 16384;           // [32,512]
  float* rw     = ws + 4 * M;           // [32,512,512] unnormalized weights
  float* t3     = ws + 12 * M;          // 3x [2048,512]
  float* att    = ws + 15 * M;          // [2048,512] row-major [B,S,E]
  float* to_    = ws + 16 * M;          // [2048,512]

  k_gemm_mfma<<<dim3(32, 8, 3), 256, 0, stream>>>(query, key_, value, Wq, Wk, Wv, t3);
  k_post<<<dim3(2048, 3), 256, 0, stream>>>(t3, bq, bk, bv, Qb, Kb, Vb, qn, kn, vn,
                                            rowsum, 0);
  k_logits<<<dim3(8, 8, 32), 256, 0, stream>>>(Qb, Kb, qn, kn, rw, rowsum);
  k_scan<<<512, 256, 0, stream>>>(Vb, vn, rw, rowsum, att);
  k_gemm_mfma<<<dim3(32, 8, 1), 256, 0, stream>>>(att, att, att, Wo, Wo, Wo, to_);
  k_post<<<dim3(2048, 1), 256, 0, stream>>>(to_, bo, bo, bo, (float*)d_out,
                                            nullptr, nullptr, nullptr, nullptr, nullptr,
                                            nullptr, 1);
}